// Round 5
// baseline (270.351 us; speedup 1.0000x reference)
//
#include <hip/hip_runtime.h>

// Problem constants
#define NB 2
#define DD 192
#define HH 192
#define WW 192
#define HWSZ (HH * WW)               // 36864
#define C1F 0.0001f                  // 0.01^2
#define C2F 0.0009f                  // 0.03^2

// Tiling: each block = 16(H) x 32(W) output tile, streams along D in chunks.
#define TH 16
#define TW 32
#define CHUNK 32
#define NCH (DD / CHUNK)             // 6
#define NTH (HH / TH)                // 12
#define NTW (WW / TW)                // 6
#define NBLK (NB * NCH * NTH * NTW)  // 864

// Gaussian weights, WIN=11, sigma=1.5 (normalized, double-precision derived)
#define KWLIST { 0.00102838f, 0.00759876f, 0.03600077f, 0.10936071f, 0.21300556f, \
                 0.26601172f, 0.21300556f, 0.10936071f, 0.03600077f, 0.00759876f, 0.00102838f }

// ---------------------------------------------------------------------------
// Fused streaming SSIM kernel with a SHIFT-REGISTER D-blur (no mod-ring
// aliasing: pending[f][i] accumulates output z = d+5-i; after slice d,
// pending[*][10] == completed out[d-5]; pre-chunk z's are discarded by the
// consume guard t>=10 and shifted out).
// ---------------------------------------------------------------------------
__global__ __launch_bounds__(512, 2) void ssim_fused(
    const float* __restrict__ x, const float* __restrict__ y,
    float* __restrict__ partials) {
  const float KW[11] = KWLIST;

  int bid = blockIdx.x;
  const int tw = bid % NTW; bid /= NTW;
  const int th = bid % NTH; bid /= NTH;
  const int c  = bid % NCH; bid /= NCH;
  const int b  = bid;                       // 0..1
  const int h0 = th * TH, w0 = tw * TW, c0 = c * CHUNK;

  __shared__ float  sx[TH + 10][TW + 10];   // 26 x 42 staged x
  __shared__ float  sy[TH + 10][TW + 10];   // 26 x 42 staged y
  __shared__ float4 t4[TH + 10][TW];        // W-blurred fields 0..3
  __shared__ float  t1[TH + 10][TW];        // W-blurred field 4

  const int tid = threadIdx.x;
  const int hh  = tid >> 5;                 // 0..15 (own H row)
  const int wl  = tid & 31;                 // 0..31 (own W col)

  const float* xb = x + (size_t)b * DD * HWSZ;
  const float* yb = y + (size_t)b * DD * HWSZ;

  // Shift register: pending[f][i] accumulates output z = d + 5 - i.
  float pend[5][11];
#pragma unroll
  for (int f = 0; f < 5; ++f)
#pragma unroll
    for (int i = 0; i < 11; ++i) pend[f][i] = 0.f;

  float lsum = 0.f;

  // Steps t = 0 .. CHUNK+9. Slice d = c0 - 5 + t. Output z = d - 5 completes
  // at the end of step t; valid (in-chunk) outputs are t >= 10.
  for (int t = 0; t < CHUNK + 10; ++t) {
    const int d = c0 - 5 + t;

    if (d >= 0 && d < DD) {
      const float* xs = xb + (size_t)d * HWSZ;
      const float* ys = yb + (size_t)d * HWSZ;

      // --- stage 26x42 tiles of x and y (zero-padded) ---
      for (int q = tid; q < (TH + 10) * (TW + 10); q += 512) {
        int i = q / (TW + 10), j = q % (TW + 10);
        int gh = h0 - 5 + i, gw = w0 - 5 + j;
        float vx = 0.f, vy = 0.f;
        if ((unsigned)gh < (unsigned)HH && (unsigned)gw < (unsigned)WW) {
          int o = gh * WW + gw;
          vx = xs[o];
          vy = ys[o];
        }
        sx[i][j] = vx;
        sy[i][j] = vy;
      }
      __syncthreads();

      // --- W-blur: 26 rows x 32 cols, 5 fields ---
      for (int q = tid; q < (TH + 10) * TW; q += 512) {
        int i = q >> 5, j = q & 31;
        float a0 = 0.f, a1 = 0.f, a2 = 0.f, a3 = 0.f, a4 = 0.f;
#pragma unroll
        for (int u = 0; u < 11; ++u) {
          float k = KW[u];
          float vx = sx[i][j + u];
          float vy = sy[i][j + u];
          a0 += k * vx;
          a1 += k * vy;
          a2 += k * (vx * vx);
          a3 += k * (vy * vy);
          a4 += k * (vx * vy);
        }
        t4[i][j] = make_float4(a0, a1, a2, a3);
        t1[i][j] = a4;
      }
      __syncthreads();

      // --- H-blur: own (hh, wl) voxel, 5 fields ---
      float s0 = 0.f, s1 = 0.f, s2 = 0.f, s3 = 0.f, s4 = 0.f;
#pragma unroll
      for (int u = 0; u < 11; ++u) {
        float k = KW[u];
        float4 v = t4[hh + u][wl];
        float v4 = t1[hh + u][wl];
        s0 += k * v.x;
        s1 += k * v.y;
        s2 += k * v.z;
        s3 += k * v.w;
        s4 += k * v4;
      }

      // --- accumulate: slice d contributes KW[i] to output z = d+5-i ---
#pragma unroll
      for (int i = 0; i < 11; ++i) {
        const float w = KW[i];
        pend[0][i] += w * s0;
        pend[1][i] += w * s1;
        pend[2][i] += w * s2;
        pend[3][i] += w * s3;
        pend[4][i] += w * s4;
      }
    }

    // --- consume: pending[*][10] == out[z], z = d-5 = c0 + t - 10 ---
    if (t >= 10) {
      float mu1 = pend[0][10], mu2 = pend[1][10];
      float mu1sq = mu1 * mu1, mu2sq = mu2 * mu2, mu12 = mu1 * mu2;
      float v1 = pend[2][10] - mu1sq;
      float v2 = pend[3][10] - mu2sq;
      float v12 = pend[4][10] - mu12;
      float num = (2.f * mu12 + C1F) * (2.f * v12 + C2F);
      float den = (mu1sq + mu2sq + C1F) * (v1 + v2 + C2F);
      lsum += num / den;
    }

    // --- shift: pending[i] <- pending[i-1], pending[0] <- 0 ---
#pragma unroll
    for (int f = 0; f < 5; ++f) {
#pragma unroll
      for (int i = 10; i > 0; --i) pend[f][i] = pend[f][i - 1];
      pend[f][0] = 0.f;
    }
  }

  // --- block reduction: 8 waves ---
  for (int off = 32; off > 0; off >>= 1) lsum += __shfl_down(lsum, off, 64);
  __shared__ float wsum[8];
  if ((tid & 63) == 0) wsum[tid >> 6] = lsum;
  __syncthreads();
  if (tid == 0) {
    float s = 0.f;
#pragma unroll
    for (int i = 0; i < 8; ++i) s += wsum[i];
    partials[blockIdx.x] = s;
  }
}

// ---------------------------------------------------------------------------
// Final reduction: NBLK partials -> mean, deterministic, double accumulate.
// ---------------------------------------------------------------------------
__global__ __launch_bounds__(256) void ssim_reduce(
    const float* __restrict__ partials, float* __restrict__ out) {
  __shared__ double sd[256];
  double a = 0.0;
  for (int i = threadIdx.x; i < NBLK; i += 256) a += (double)partials[i];
  sd[threadIdx.x] = a;
  __syncthreads();
  for (int s = 128; s > 0; s >>= 1) {
    if ((int)threadIdx.x < s) sd[threadIdx.x] += sd[threadIdx.x + s];
    __syncthreads();
  }
  if (threadIdx.x == 0) {
    out[0] = (float)(sd[0] / (double)((size_t)NB * DD * HH * WW));
  }
}

extern "C" void kernel_launch(void* const* d_in, const int* in_sizes, int n_in,
                              void* d_out, int out_size, void* d_ws, size_t ws_size,
                              hipStream_t stream) {
  const float* img1 = (const float*)d_in[0];
  const float* img2 = (const float*)d_in[1];
  float* out = (float*)d_out;
  float* partials = (float*)d_ws;   // NBLK floats = 3456 B, well within ws

  ssim_fused<<<NBLK, 512, 0, stream>>>(img1, img2, partials);
  ssim_reduce<<<1, 256, 0, stream>>>(partials, out);
}

// Round 6
// 194.440 us; speedup vs baseline: 1.3904x; 1.3904x over previous
//
#include <hip/hip_runtime.h>

// Problem constants
#define NB 2
#define DD 192
#define HH 192
#define WW 192
#define HWSZ (HH * WW)
#define C1F 0.0001f
#define C2F 0.0009f

// Tiling
#define TH 16
#define TW 32
#define CHUNK 32
#define TSTEPS (CHUNK + 10)          // 42
#define NCH (DD / CHUNK)             // 6
#define NTH (HH / TH)                // 12
#define NTW (WW / TW)                // 6
#define NBLK (NB * NCH * NTH * NTW)  // 864

#define SH (TH + 10)                 // 26 staged rows
#define SWQ 12                       // float4 quads per staged row
#define SW (4 * SWQ)                 // 48 staged cols (global w0-8 .. w0+39)

// Gaussian weights, WIN=11, sigma=1.5
#define KWLIST { 0.00102838f, 0.00759876f, 0.03600077f, 0.10936071f, 0.21300556f, \
                 0.26601172f, 0.21300556f, 0.10936071f, 0.03600077f, 0.00759876f, 0.00102838f }

// ---------------------------------------------------------------------------
// Fused streaming SSIM: per slice d stage {x,y,x2,y2} (float4/col, vectorized,
// hoisted addressing, prefetched), W-blur -> t4/t1, H-blur -> s0..s4, D-blur
// via mod-11 ring with COMPILE-TIME slots (11-phase unroll) and unconditional
// clear-after-consume (closes the R2 aliasing: pollution slot r%11 is cleared
// at t=r+10 before z=r+11 starts accumulating at t=r+11).
// ---------------------------------------------------------------------------
__global__ __launch_bounds__(512, 2) void ssim_fused(
    const float* __restrict__ x, const float* __restrict__ y,
    float* __restrict__ partials) {
  const float KW[11] = KWLIST;

  int bid = blockIdx.x;
  const int tw = bid % NTW; bid /= NTW;
  const int th = bid % NTH; bid /= NTH;
  const int c  = bid % NCH; bid /= NCH;
  const int b  = bid;
  const int h0 = th * TH, w0 = tw * TW, c0 = c * CHUNK;

  __shared__ float4 s4[SH][SW];   // staged {x, y, x2, y2} per column
  __shared__ float4 t4[SH][TW];   // W-blurred {bx, by, bx2, by2}
  __shared__ float  t1[SH][TW];   // W-blurred xy

  const int tid = threadIdx.x;
  const int hh  = tid >> 5;       // 0..15
  const int wl  = tid & 31;       // 0..31

  // ---- hoisted stage addressing: 26*12 = 312 quad tasks (step-invariant) ----
  const int  sr   = tid / SWQ;
  const int  sq   = tid % SWQ;
  const bool sAct = (tid < SH * SWQ);
  const int  sgh  = h0 - 5 + sr;
  const int  sgw  = w0 - 8 + 4 * sq;   // quad is fully in [0,WW) or fully out
  const bool sIn  = sAct && (unsigned)sgh < (unsigned)HH && (unsigned)sgw < (unsigned)WW;
  const int  sOff = sgh * WW + sgw;

  // OOB quads are zero for the whole kernel: write once.
  if (sAct && !sIn) {
    const float4 z4 = make_float4(0.f, 0.f, 0.f, 0.f);
    s4[sr][4 * sq + 0] = z4; s4[sr][4 * sq + 1] = z4;
    s4[sr][4 * sq + 2] = z4; s4[sr][4 * sq + 3] = z4;
  }

  // W-blur second task (rows 16..25) for threads hh < 10
  const bool w2 = (hh < SH - TH);

  const float* xb = x + (size_t)b * DD * HWSZ;
  const float* yb = y + (size_t)b * DD * HWSZ;

  // Ring accumulators, slot(z) = (z - c0) mod 11, all indices compile-time.
  float pend[5][11];
#pragma unroll
  for (int f = 0; f < 5; ++f)
#pragma unroll
    for (int i = 0; i < 11; ++i) pend[f][i] = 0.f;

  float lsum = 0.f;

  // Preload slice t=0 (d = c0-5; invalid only for c=0, handled by guard).
  float4 xv = make_float4(0.f, 0.f, 0.f, 0.f), yv = xv;
  {
    const int d0 = c0 - 5;
    if (d0 >= 0 && sIn) {
      xv = *(const float4*)(xb + (size_t)d0 * HWSZ + sOff);
      yv = *(const float4*)(yb + (size_t)d0 * HWSZ + sOff);
    }
  }

  for (int m = 0; m < 4; ++m) {
#pragma unroll
    for (int p = 0; p < 11; ++p) {
      const int t = m * 11 + p;
      if (t < TSTEPS) {
        const int d = c0 - 5 + t;
        const bool dv = (d >= 0) && (d < DD);   // uniform across block

        if (dv) {
          // ---- stage: write prefetched slice to LDS ----
          if (sIn) {
            s4[sr][4 * sq + 0] = make_float4(xv.x, yv.x, xv.x * xv.x, yv.x * yv.x);
            s4[sr][4 * sq + 1] = make_float4(xv.y, yv.y, xv.y * xv.y, yv.y * yv.y);
            s4[sr][4 * sq + 2] = make_float4(xv.z, yv.z, xv.z * xv.z, yv.z * yv.z);
            s4[sr][4 * sq + 3] = make_float4(xv.w, yv.w, xv.w * xv.w, yv.w * yv.w);
          }
          __syncthreads();

          // ---- W-blur: row hh (all threads) + row hh+16 (hh<10) ----
          {
            float4 a = make_float4(0.f, 0.f, 0.f, 0.f); float axy = 0.f;
#pragma unroll
            for (int u = 0; u < 11; ++u) {
              const float  k = KW[u];
              const float4 v = s4[hh][wl + 3 + u];
              a.x += k * v.x; a.y += k * v.y; a.z += k * v.z; a.w += k * v.w;
              axy += k * (v.x * v.y);
            }
            t4[hh][wl] = a; t1[hh][wl] = axy;
          }
          if (w2) {
            float4 a = make_float4(0.f, 0.f, 0.f, 0.f); float axy = 0.f;
#pragma unroll
            for (int u = 0; u < 11; ++u) {
              const float  k = KW[u];
              const float4 v = s4[hh + TH][wl + 3 + u];
              a.x += k * v.x; a.y += k * v.y; a.z += k * v.z; a.w += k * v.w;
              axy += k * (v.x * v.y);
            }
            t4[hh + TH][wl] = a; t1[hh + TH][wl] = axy;
          }
          __syncthreads();
        }

        // ---- prefetch slice t+1 (hides HBM/L2 latency under H-blur) ----
        {
          const int dn = d + 1;
          if ((t + 1) < TSTEPS && dn >= 0 && dn < DD && sIn) {
            xv = *(const float4*)(xb + (size_t)dn * HWSZ + sOff);
            yv = *(const float4*)(yb + (size_t)dn * HWSZ + sOff);
          }
        }

        if (dv) {
          // ---- H-blur: own (hh, wl) voxel ----
          float s0 = 0.f, s1 = 0.f, s2 = 0.f, s3 = 0.f, sx4 = 0.f;
#pragma unroll
          for (int u = 0; u < 11; ++u) {
            const float  k  = KW[u];
            const float4 v  = t4[hh + u][wl];
            const float  v1 = t1[hh + u][wl];
            s0 += k * v.x; s1 += k * v.y; s2 += k * v.z; s3 += k * v.w;
            sx4 += k * v1;
          }
          // ---- ring accumulate: slot (p+1+kk)%11, weight KW[kk] ----
#pragma unroll
          for (int kk = 0; kk < 11; ++kk) {
            const int   sl  = (p + 1 + kk) % 11;
            const float wgt = KW[kk];
            pend[0][sl] += wgt * s0;
            pend[1][sl] += wgt * s1;
            pend[2][sl] += wgt * s2;
            pend[3][sl] += wgt * s3;
            pend[4][sl] += wgt * sx4;
          }
        }

        // ---- consume (t>=10) & unconditional clear of slot (p+1)%11 ----
        {
          const int sc = (p + 1) % 11;
          if (t >= 10) {
            const float mu1 = pend[0][sc], mu2 = pend[1][sc];
            const float mu1sq = mu1 * mu1, mu2sq = mu2 * mu2, mu12 = mu1 * mu2;
            const float v1  = pend[2][sc] - mu1sq;
            const float v2  = pend[3][sc] - mu2sq;
            const float v12 = pend[4][sc] - mu12;
            const float num = (2.f * mu12 + C1F) * (2.f * v12 + C2F);
            const float den = (mu1sq + mu2sq + C1F) * (v1 + v2 + C2F);
            lsum += num * __builtin_amdgcn_rcpf(den);
          }
          pend[0][sc] = 0.f; pend[1][sc] = 0.f; pend[2][sc] = 0.f;
          pend[3][sc] = 0.f; pend[4][sc] = 0.f;
        }
      }
    }
  }

  // ---- block reduction: 8 waves ----
  for (int off = 32; off > 0; off >>= 1) lsum += __shfl_down(lsum, off, 64);
  __shared__ float wsum[8];
  if ((tid & 63) == 0) wsum[tid >> 6] = lsum;
  __syncthreads();
  if (tid == 0) {
    float s = 0.f;
#pragma unroll
    for (int i = 0; i < 8; ++i) s += wsum[i];
    partials[blockIdx.x] = s;
  }
}

// ---------------------------------------------------------------------------
// Final reduction: NBLK partials -> mean (deterministic, double).
// ---------------------------------------------------------------------------
__global__ __launch_bounds__(256) void ssim_reduce(
    const float* __restrict__ partials, float* __restrict__ out) {
  __shared__ double sd[256];
  double a = 0.0;
  for (int i = threadIdx.x; i < NBLK; i += 256) a += (double)partials[i];
  sd[threadIdx.x] = a;
  __syncthreads();
  for (int s = 128; s > 0; s >>= 1) {
    if ((int)threadIdx.x < s) sd[threadIdx.x] += sd[threadIdx.x + s];
    __syncthreads();
  }
  if (threadIdx.x == 0) {
    out[0] = (float)(sd[0] / (double)((size_t)NB * DD * HH * WW));
  }
}

extern "C" void kernel_launch(void* const* d_in, const int* in_sizes, int n_in,
                              void* d_out, int out_size, void* d_ws, size_t ws_size,
                              hipStream_t stream) {
  const float* img1 = (const float*)d_in[0];
  const float* img2 = (const float*)d_in[1];
  float* out = (float*)d_out;
  float* partials = (float*)d_ws;   // NBLK floats

  ssim_fused<<<NBLK, 512, 0, stream>>>(img1, img2, partials);
  ssim_reduce<<<1, 256, 0, stream>>>(partials, out);
}

// Round 7
// 169.453 us; speedup vs baseline: 1.5954x; 1.1475x over previous
//
#include <hip/hip_runtime.h>

// Problem constants
#define NB 2
#define DD 192
#define HH 192
#define WW 192
#define HWSZ (HH * WW)
#define C1F 0.0001f
#define C2F 0.0009f

// Tiling: 16(H) x 32(W) outputs per block-slice, 256 threads, stream D.
#define TH 16
#define TW 32
#define CHUNK 32
#define TSTEPS (CHUNK + 10)          // 42
#define NCH (DD / CHUNK)             // 6
#define NTH (HH / TH)                // 12
#define NTW (WW / TW)                // 6
#define NBLK (NB * NCH * NTH * NTW)  // 864

#define SROWS (TH + 10)              // 26 staged/W-blurred rows
#define SCOLS 42                     // staged cols (w0-5 .. w0+36)
#define SPAD 43                      // s4 row stride in quads (odd -> bank-even)
#define TPAD 33                      // t4 row stride in quads (odd -> bank-even)
#define NSTG (SROWS * SCOLS)         // 1092 stage tasks
#define NWT (SROWS * (TW / 4))       // 208 W-blur tasks

// Gaussian weights, WIN=11, sigma=1.5
#define KWLIST { 0.00102838f, 0.00759876f, 0.03600077f, 0.10936071f, 0.21300556f, \
                 0.26601172f, 0.21300556f, 0.10936071f, 0.03600077f, 0.00759876f, 0.00102838f }

// SSIM from 4 packed stats: mu1, mu2, A=blur((x+y)^2), Bm=blur((x-y)^2).
// E[x^2]+E[y^2] = (A+Bm)/2 ; E[xy] = (A-Bm)/4.
__device__ __forceinline__ float ssim_val(float mu1, float mu2, float A, float Bm) {
  const float mu1sq = mu1 * mu1, mu2sq = mu2 * mu2, mu12 = mu1 * mu2;
  const float num = (2.f * mu12 + C1F) * (0.5f * (A - Bm) - 2.f * mu12 + C2F);
  const float den = (mu1sq + mu2sq + C1F) * (0.5f * (A + Bm) - mu1sq - mu2sq + C2F);
  return num * __builtin_amdgcn_rcpf(den);
}

__global__ __launch_bounds__(256) void ssim_fused(
    const float* __restrict__ x, const float* __restrict__ y,
    float* __restrict__ partials) {
  const float KW[11] = KWLIST;

  int bid = blockIdx.x;
  const int tw = bid % NTW; bid /= NTW;
  const int th = bid % NTH; bid /= NTH;
  const int c  = bid % NCH; bid /= NCH;
  const int b  = bid;
  const int h0 = th * TH, w0 = tw * TW, c0 = c * CHUNK;

  __shared__ float4 s4[SROWS][SPAD];   // staged {x, y, (x+y)^2, (x-y)^2}
  __shared__ float4 t4[SROWS][TPAD];   // W-blurred 4 fields

  const int tid = threadIdx.x;
  const int cl  = tid & 31;            // own W col
  const int rg  = tid >> 5;            // 0..7 row-group
  const int r0  = 2 * rg;              // own output rows r0, r0+1

  // ---- hoisted stage-task addressing: 1092 quad tasks, 5 rounds ----
  int  sIdx[5], sOff[5];
  bool sOk[5];
#pragma unroll
  for (int k = 0; k < 5; ++k) {
    const int q = tid + 256 * k;
    const bool act = (q < NSTG);
    const int row = q / SCOLS, col = q % SCOLS;
    const int gh = h0 - 5 + row, gw = w0 - 5 + col;
    sOk[k]  = act && (unsigned)gh < (unsigned)HH && (unsigned)gw < (unsigned)WW;
    sIdx[k] = row * SPAD + col;
    sOff[k] = gh * WW + gw;
  }
  // W-blur task addressing (208 tasks)
  const bool wAct = (tid < NWT);
  const int  wr = tid >> 3;            // 0..25
  const int  wq = tid & 7;             // 0..7 (out quad group)

  // zero-init s4 once (OOB quads stay zero all kernel)
  {
    const float4 z = make_float4(0.f, 0.f, 0.f, 0.f);
    for (int q = tid; q < SROWS * SPAD; q += 256) (&s4[0][0])[q] = z;
  }
  __syncthreads();

  const float* xb = x + (size_t)b * DD * HWSZ;
  const float* yb = y + (size_t)b * DD * HWSZ;

  // Ring accumulators (2 output rows x 4 fields x 11 slots), compile-time idx.
  float pend0[4][11], pend1[4][11];
#pragma unroll
  for (int f = 0; f < 4; ++f)
#pragma unroll
    for (int i = 0; i < 11; ++i) { pend0[f][i] = 0.f; pend1[f][i] = 0.f; }

  float px[5], py[5];
#pragma unroll
  for (int k = 0; k < 5; ++k) { px[k] = 0.f; py[k] = 0.f; }

  // pre-loop prefetch of slice t=0 (d = c0-5), only valid for c>0
  if (c0 >= 5) {
    const float* xs = xb + (size_t)(c0 - 5) * HWSZ;
    const float* ys = yb + (size_t)(c0 - 5) * HWSZ;
#pragma unroll
    for (int k = 0; k < 5; ++k)
      if (sOk[k]) { px[k] = xs[sOff[k]]; py[k] = ys[sOff[k]]; }
  }

  float lsum = 0.f;
  int p = 0;   // t mod 11 (wave-uniform)

  for (int t = 0; t < TSTEPS; ++t) {
    const int d = c0 - 5 + t;
    const bool dv = (d >= 0) && (d < DD);   // block-uniform

    if (dv) {
      // ---- stage prefetched slice ----
#pragma unroll
      for (int k = 0; k < 5; ++k)
        if (sOk[k]) {
          const float xx = px[k], yy = py[k];
          const float sm = xx + yy, df = xx - yy;
          (&s4[0][0])[sIdx[k]] = make_float4(xx, yy, sm * sm, df * df);
        }
    }
    // ---- prefetch slice t+1 (latency hidden under W/H compute) ----
    {
      const int dn = d + 1;
      if ((t + 1) < TSTEPS && dn >= 0 && dn < DD) {
        const float* xs = xb + (size_t)dn * HWSZ;
        const float* ys = yb + (size_t)dn * HWSZ;
#pragma unroll
        for (int k = 0; k < 5; ++k)
          if (sOk[k]) { px[k] = xs[sOff[k]]; py[k] = ys[sOff[k]]; }
      }
    }

    float4 B0 = make_float4(0.f, 0.f, 0.f, 0.f);
    float4 B1 = B0;

    if (dv) {
      __syncthreads();
      // ---- W-blur: 4 outputs per task via sliding window (14 reads) ----
      if (wAct) {
        float4 a0 = make_float4(0.f, 0.f, 0.f, 0.f), a1 = a0, a2 = a0, a3 = a0;
#pragma unroll
        for (int u = 0; u < 14; ++u) {
          const float4 v = s4[wr][4 * wq + u];
          if (u <= 10)           { const float k = KW[u];     a0.x += k*v.x; a0.y += k*v.y; a0.z += k*v.z; a0.w += k*v.w; }
          if (u >= 1 && u <= 11) { const float k = KW[u - 1]; a1.x += k*v.x; a1.y += k*v.y; a1.z += k*v.z; a1.w += k*v.w; }
          if (u >= 2 && u <= 12) { const float k = KW[u - 2]; a2.x += k*v.x; a2.y += k*v.y; a2.z += k*v.z; a2.w += k*v.w; }
          if (u >= 3)            { const float k = KW[u - 3]; a3.x += k*v.x; a3.y += k*v.y; a3.z += k*v.z; a3.w += k*v.w; }
        }
        t4[wr][4 * wq + 0] = a0;
        t4[wr][4 * wq + 1] = a1;
        t4[wr][4 * wq + 2] = a2;
        t4[wr][4 * wq + 3] = a3;
      }
      __syncthreads();

      // ---- H-blur: 2 output rows per thread via sliding window (12 reads) ----
#pragma unroll
      for (int u = 0; u < 12; ++u) {
        const float4 v = t4[r0 + u][cl];
        if (u <= 10) { const float k = KW[u];     B0.x += k*v.x; B0.y += k*v.y; B0.z += k*v.z; B0.w += k*v.w; }
        if (u >= 1)  { const float k = KW[u - 1]; B1.x += k*v.x; B1.y += k*v.y; B1.z += k*v.z; B1.w += k*v.w; }
      }
    }

    // ---- D-ring: compile-time slots via switch on p = t % 11 ----
#define RING_CASE(P)                                                        \
    case P: {                                                               \
      if (dv) {                                                             \
        _Pragma("unroll")                                                   \
        for (int kk = 0; kk < 11; ++kk) {                                   \
          const int   sl = (P + 1 + kk) % 11;                               \
          const float wg = KW[kk];                                          \
          pend0[0][sl] += wg * B0.x; pend0[1][sl] += wg * B0.y;             \
          pend0[2][sl] += wg * B0.z; pend0[3][sl] += wg * B0.w;             \
          pend1[0][sl] += wg * B1.x; pend1[1][sl] += wg * B1.y;             \
          pend1[2][sl] += wg * B1.z; pend1[3][sl] += wg * B1.w;             \
        }                                                                   \
      }                                                                     \
      const int sc = (P + 1) % 11;                                          \
      if (t >= 10) {                                                        \
        lsum += ssim_val(pend0[0][sc], pend0[1][sc], pend0[2][sc], pend0[3][sc]); \
        lsum += ssim_val(pend1[0][sc], pend1[1][sc], pend1[2][sc], pend1[3][sc]); \
      }                                                                     \
      pend0[0][sc] = 0.f; pend0[1][sc] = 0.f;                               \
      pend0[2][sc] = 0.f; pend0[3][sc] = 0.f;                               \
      pend1[0][sc] = 0.f; pend1[1][sc] = 0.f;                               \
      pend1[2][sc] = 0.f; pend1[3][sc] = 0.f;                               \
    } break;

    switch (p) {
      RING_CASE(0) RING_CASE(1) RING_CASE(2) RING_CASE(3) RING_CASE(4)
      RING_CASE(5) RING_CASE(6) RING_CASE(7) RING_CASE(8) RING_CASE(9)
      RING_CASE(10)
    }
#undef RING_CASE
    p = (p + 1 == 11) ? 0 : p + 1;
  }

  // ---- block reduction: 4 waves ----
  for (int off = 32; off > 0; off >>= 1) lsum += __shfl_down(lsum, off, 64);
  __shared__ float wsum[4];
  if ((tid & 63) == 0) wsum[tid >> 6] = lsum;
  __syncthreads();
  if (tid == 0) partials[blockIdx.x] = wsum[0] + wsum[1] + wsum[2] + wsum[3];
}

// ---------------------------------------------------------------------------
// Final reduction: NBLK partials -> mean (deterministic, double).
// ---------------------------------------------------------------------------
__global__ __launch_bounds__(256) void ssim_reduce(
    const float* __restrict__ partials, float* __restrict__ out) {
  __shared__ double sd[256];
  double a = 0.0;
  for (int i = threadIdx.x; i < NBLK; i += 256) a += (double)partials[i];
  sd[threadIdx.x] = a;
  __syncthreads();
  for (int s = 128; s > 0; s >>= 1) {
    if ((int)threadIdx.x < s) sd[threadIdx.x] += sd[threadIdx.x + s];
    __syncthreads();
  }
  if (threadIdx.x == 0) {
    out[0] = (float)(sd[0] / (double)((size_t)NB * DD * HH * WW));
  }
}

extern "C" void kernel_launch(void* const* d_in, const int* in_sizes, int n_in,
                              void* d_out, int out_size, void* d_ws, size_t ws_size,
                              hipStream_t stream) {
  const float* img1 = (const float*)d_in[0];
  const float* img2 = (const float*)d_in[1];
  float* out = (float*)d_out;
  float* partials = (float*)d_ws;   // NBLK floats

  ssim_fused<<<NBLK, 256, 0, stream>>>(img1, img2, partials);
  ssim_reduce<<<1, 256, 0, stream>>>(partials, out);
}